// Round 9
// baseline (252.779 us; speedup 1.0000x reference)
//
#include <hip/hip_runtime.h>
#include <cstdint>

// ---------------------------------------------------------------------------
// DefaultAttention: x[4,2048,1024] fp32; k=xWk^T+bk, q=xWq^T+bq, v=xWv^T+bv;
// sim = k q^T / 32 (causal tril), attn = softmax(sim), out = attn @ v (fp32).
// R9: scores/pv move to 512-thread blocks (8 waves, 2x4 wave grid, 64x32 per
// wave) -> 16 waves/CU instead of 8 in their all-resident single-round
// regime (they were ds_read-latency-bound at 2 waves/SIMD). Same 128x128
// tile, same traffic, same verified dbuf+XOR-swizzle pipeline. qkv = R8.
// ---------------------------------------------------------------------------

typedef __attribute__((ext_vector_type(8))) _Float16 f16x8;
typedef __attribute__((ext_vector_type(4))) float f32x4;

__device__ __forceinline__ unsigned short f2h(float x) {
  return __builtin_bit_cast(unsigned short, (_Float16)x);
}

// async global->LDS, 16B per lane; LDS dest = wave-uniform base + lane*16
__device__ __forceinline__ void lds_dma16(const void* g, void* l) {
  auto gp = reinterpret_cast<const __attribute__((address_space(1))) void*>(
      reinterpret_cast<uintptr_t>(g));
  auto lp = reinterpret_cast<__attribute__((address_space(3))) void*>(
      reinterpret_cast<uintptr_t>(l));
  __builtin_amdgcn_global_load_lds(gp, lp, 16, 0, 0);
}

// ---------------------------------------------------------------------------
// gemm128 (dbuf, 256 thr): C[128x128] += A[128xK] * B[128xK]^T. BK=32,
// XOR-swizzled LDS, double-buffered single-barrier pipeline (R4-verified).
// ---------------------------------------------------------------------------
__device__ __forceinline__ void gemm128(const unsigned short* __restrict__ Ag,
                                        const unsigned short* __restrict__ Bg,
                                        int lda, int ldb, int nk,
                                        unsigned short* As, unsigned short* Bs,
                                        f32x4 acc[4][4]) {
  const int tid = threadIdx.x;
  const int lane = tid & 63, wave = tid >> 6;
  const int wm = wave >> 1, wn = wave & 1;
  const int sr = lane >> 2;                               // staging row in chunk
  const int scb = (((lane & 3) ^ ((lane >> 3) & 3)) * 8); // swizzled src col
  const int rr = lane & 15, qq = lane >> 4;
  const int slot = ((qq ^ ((rr >> 1) & 3)) * 8);          // swizzled read col

#pragma unroll
  for (int i = 0; i < 4; ++i)
#pragma unroll
    for (int j = 0; j < 4; ++j) {
      f32x4 z = {0.f, 0.f, 0.f, 0.f};
      acc[i][j] = z;
    }

#pragma unroll
  for (int c = 0; c < 2; ++c) {
    int chunk = wave * 2 + c;
    int row = chunk * 16 + sr;
    lds_dma16(Ag + (size_t)row * lda + scb, As + chunk * 512);
    lds_dma16(Bg + (size_t)row * ldb + scb, Bs + chunk * 512);
  }

  int buf = 0;
  for (int k0 = 0; k0 < nk; k0 += 32) {
    __syncthreads();  // drains staging issued one compute-phase ago
    const int kn = k0 + 32;
    if (kn < nk) {
      unsigned short* An = As + (buf ^ 1) * 4096;
      unsigned short* Bn = Bs + (buf ^ 1) * 4096;
#pragma unroll
      for (int c = 0; c < 2; ++c) {
        int chunk = wave * 2 + c;
        int row = chunk * 16 + sr;
        lds_dma16(Ag + (size_t)row * lda + kn + scb, An + chunk * 512);
        lds_dma16(Bg + (size_t)row * ldb + kn + scb, Bn + chunk * 512);
      }
    }

    f16x8 af[4], bf[4];
    const unsigned short* Ar = As + buf * 4096 + (wm * 64 + rr) * 32 + slot;
    const unsigned short* Br = Bs + buf * 4096 + (wn * 64 + rr) * 32 + slot;
#pragma unroll
    for (int i = 0; i < 4; ++i) af[i] = *(const f16x8*)(Ar + i * 512);
#pragma unroll
    for (int j = 0; j < 4; ++j) bf[j] = *(const f16x8*)(Br + j * 512);
#pragma unroll
    for (int i = 0; i < 4; ++i)
#pragma unroll
      for (int j = 0; j < 4; ++j)
        acc[i][j] = __builtin_amdgcn_mfma_f32_16x16x32_f16(af[i], bf[j],
                                                           acc[i][j], 0, 0, 0);
    buf ^= 1;
  }
}

// ---------------------------------------------------------------------------
// gemm128_w8 (dbuf, 512 thr): same tile, 8 waves in 2x4 grid; wave owns
// 64x32 (4x2 frags, 32 AGPR). Wave w stages A-chunk w and B-chunk w.
// ---------------------------------------------------------------------------
__device__ __forceinline__ void gemm128_w8(
    const unsigned short* __restrict__ Ag, const unsigned short* __restrict__ Bg,
    int lda, int ldb, int nk, unsigned short* As, unsigned short* Bs,
    f32x4 acc[4][2]) {
  const int tid = threadIdx.x;
  const int lane = tid & 63, wave = tid >> 6;            // 0..7
  const int wm = wave >> 2, wn = wave & 3;               // 2 x 4
  const int sr = lane >> 2;
  const int scb = (((lane & 3) ^ ((lane >> 3) & 3)) * 8);
  const int rr = lane & 15, qq = lane >> 4;
  const int slot = ((qq ^ ((rr >> 1) & 3)) * 8);

#pragma unroll
  for (int i = 0; i < 4; ++i)
#pragma unroll
    for (int j = 0; j < 2; ++j) {
      f32x4 z = {0.f, 0.f, 0.f, 0.f};
      acc[i][j] = z;
    }

  {
    int row = wave * 16 + sr;
    lds_dma16(Ag + (size_t)row * lda + scb, As + wave * 512);
    lds_dma16(Bg + (size_t)row * ldb + scb, Bs + wave * 512);
  }

  int buf = 0;
  for (int k0 = 0; k0 < nk; k0 += 32) {
    __syncthreads();
    const int kn = k0 + 32;
    if (kn < nk) {
      int row = wave * 16 + sr;
      lds_dma16(Ag + (size_t)row * lda + kn + scb,
                As + (buf ^ 1) * 4096 + wave * 512);
      lds_dma16(Bg + (size_t)row * ldb + kn + scb,
                Bs + (buf ^ 1) * 4096 + wave * 512);
    }

    f16x8 af[4], bf[2];
    const unsigned short* Ar = As + buf * 4096 + (wm * 64 + rr) * 32 + slot;
    const unsigned short* Br = Bs + buf * 4096 + (wn * 32 + rr) * 32 + slot;
#pragma unroll
    for (int i = 0; i < 4; ++i) af[i] = *(const f16x8*)(Ar + i * 512);
#pragma unroll
    for (int j = 0; j < 2; ++j) bf[j] = *(const f16x8*)(Br + j * 512);
#pragma unroll
    for (int i = 0; i < 4; ++i)
#pragma unroll
      for (int j = 0; j < 2; ++j)
        acc[i][j] = __builtin_amdgcn_mfma_f32_16x16x32_f16(af[i], bf[j],
                                                           acc[i][j], 0, 0, 0);
    buf ^= 1;
  }
}

// ---------------------------------------------------------------------------
// fp32 -> f16 convert: x then Wk,Wq,Wv into contiguous [xh | wh];
// last 8 blocks zero rsum (8192 floats).
// ---------------------------------------------------------------------------
__global__ void cvt_kernel(const float* __restrict__ x,
                           const float* __restrict__ w0,
                           const float* __restrict__ w1,
                           const float* __restrict__ w2,
                           unsigned short* __restrict__ dst,
                           float* __restrict__ rsum) {
  int i = blockIdx.x * 256 + threadIdx.x;
  if (i >= 2883584) {
    int z2 = i - 2883584;
    float4 z = {0.f, 0.f, 0.f, 0.f};
    ((float4*)rsum)[z2] = z;
    return;
  }
  const float* s;
  size_t si;
  if (i < 2097152) {
    s = x; si = i;
  } else {
    int j = i - 2097152;
    int z = j >> 18;
    s = (z == 0) ? w0 : ((z == 1) ? w1 : w2);
    si = j & 262143;
  }
  float4 f = ((const float4*)s)[si];
  ushort4 u;
  u.x = f2h(f.x); u.y = f2h(f.y); u.z = f2h(f.z); u.w = f2h(f.w);
  ((ushort4*)dst)[i] = u;
}

// ---------------------------------------------------------------------------
// QKV projection, grid (24, 64): x = z*8 + tn (z fast -> xh slab shared by
// all 24 blocks of a tm), y = tm.
//   z=0/1: C[t, f] = xh[t-slab] . W[f-tile]^T  -> kh/qh[t*1024 + f]
//   z=2  : C[d, t] = Wv[d-tile] . xh[t-slab]^T -> vT[b][d][t]  (direct)
// ---------------------------------------------------------------------------
__global__ __launch_bounds__(256) void qkv_gemm_kernel(
    const unsigned short* __restrict__ xh, const unsigned short* __restrict__ wh,
    const float* __restrict__ bk, const float* __restrict__ bq,
    const float* __restrict__ bv, unsigned short* __restrict__ kh,
    unsigned short* __restrict__ qh, unsigned short* __restrict__ vT) {
  __shared__ unsigned short As[2 * 128 * 32], Bs[2 * 128 * 32];
  const int tn = blockIdx.x & 7, z = blockIdx.x >> 3;
  const unsigned short* W = wh + (size_t)z * 1048576;
  const int tm = blockIdx.y;

  const unsigned short* Ag = (z == 2) ? (W + (size_t)tn * 128 * 1024)
                                      : (xh + (size_t)tm * 128 * 1024);
  const unsigned short* Bg = (z == 2) ? (xh + (size_t)tm * 128 * 1024)
                                      : (W + (size_t)tn * 128 * 1024);

  f32x4 acc[4][4];
  gemm128(Ag, Bg, 1024, 1024, 1024, As, Bs, acc);

  const int lane = threadIdx.x & 63, wave = threadIdx.x >> 6;
  const int wm = wave >> 1, wn = wave & 1, rr = lane & 15, qq = lane >> 4;

  if (z == 2) {
    // rows = d, cols = t; bias is per-row (float4 over reg)
#pragma unroll
    for (int i = 0; i < 4; ++i) {
      int d0 = tn * 128 + wm * 64 + i * 16 + qq * 4;
      float4 bi = *(const float4*)(bv + d0);
      float bir[4] = {bi.x, bi.y, bi.z, bi.w};
#pragma unroll
      for (int reg = 0; reg < 4; ++reg) {
        int d = d0 + reg;
#pragma unroll
        for (int j = 0; j < 4; ++j) {
          int tg = tm * 128 + wn * 64 + j * 16 + rr;  // global token
          int bb = tg >> 11, tt = tg & 2047;
          vT[((size_t)(bb * 1024 + d)) * 2048 + tt] =
              f2h(acc[i][j][reg] + bir[reg]);
        }
      }
    }
  } else {
    const float* bias = (z == 0) ? bk : bq;
    unsigned short* dst = (z == 0) ? kh : qh;
    float bj[4];
#pragma unroll
    for (int j = 0; j < 4; ++j)
      bj[j] = bias[tn * 128 + wn * 64 + j * 16 + rr];
#pragma unroll
    for (int i = 0; i < 4; ++i)
#pragma unroll
      for (int reg = 0; reg < 4; ++reg) {
        int gm = tm * 128 + wm * 64 + i * 16 + qq * 4 + reg;
#pragma unroll
        for (int j = 0; j < 4; ++j) {
          int gc = tn * 128 + wn * 64 + j * 16 + rr;
          dst[(size_t)gm * 1024 + gc] = f2h(acc[i][j][reg] + bj[j]);
        }
      }
  }
}

// ---------------------------------------------------------------------------
// scores (512 thr): P[b,s,t] = exp(k[s].q[t]/32 - 4) for t<=s else 0 (f16),
// fused row-sum atomics. Triangular grid (136,4).
// ---------------------------------------------------------------------------
__global__ __launch_bounds__(512) void scores_kernel(
    const unsigned short* __restrict__ kh, const unsigned short* __restrict__ qh,
    unsigned short* __restrict__ P, float* __restrict__ rsum) {
  const int b = blockIdx.y;
  int idx = blockIdx.x;
  int ts = (int)((sqrtf(8.0f * idx + 1.0f) - 1.0f) * 0.5f);
  while ((ts + 1) * (ts + 2) / 2 <= idx) ++ts;
  while (ts * (ts + 1) / 2 > idx) --ts;
  const int tt = idx - ts * (ts + 1) / 2;
  __shared__ unsigned short As[2 * 128 * 32], Bs[2 * 128 * 32];

  f32x4 acc[4][2];
  gemm128_w8(kh + ((size_t)(b * 2048 + ts * 128)) * 1024,
             qh + ((size_t)(b * 2048 + tt * 128)) * 1024,
             1024, 1024, 1024, As, Bs, acc);

  const int lane = threadIdx.x & 63, wave = threadIdx.x >> 6;
  const int wm = wave >> 2, wn = wave & 3, rr = lane & 15, qq = lane >> 4;
  unsigned short* Pb = P + (size_t)b * 2048 * 2048;
  float* rs = rsum + b * 2048;
#pragma unroll
  for (int i = 0; i < 4; ++i)
#pragma unroll
    for (int reg = 0; reg < 4; ++reg) {
      int srow = ts * 128 + wm * 64 + i * 16 + qq * 4 + reg;
      float p = 0.f;
#pragma unroll
      for (int j = 0; j < 2; ++j) {
        int tcol = tt * 128 + wn * 32 + j * 16 + rr;
        float e = (tcol <= srow) ? __expf(acc[i][j][reg] * 0.03125f - 4.0f)
                                 : 0.0f;
        Pb[(size_t)srow * 2048 + tcol] = f2h(e);
        p += e;
      }
#pragma unroll
      for (int off = 1; off < 16; off <<= 1) p += __shfl_xor(p, off);
      if (rr == 0) atomicAdd(rs + srow, p);
    }
}

// ---------------------------------------------------------------------------
// pv (512 thr): out[b,s,d] = (1/rsum[b,s]) * sum_t P[b,s,t] * vT[b,d,t].
// grid (8,16,4); K truncated to (ts+1)*128; y reversed (big-K first).
// ---------------------------------------------------------------------------
__global__ __launch_bounds__(512) void pv_gemm_kernel(
    const unsigned short* __restrict__ P, const unsigned short* __restrict__ vT,
    const float* __restrict__ rsum, float* __restrict__ out) {
  const int td = blockIdx.x, ts = 15 - blockIdx.y, b = blockIdx.z;
  __shared__ unsigned short As[2 * 128 * 32], Bs[2 * 128 * 32];

  f32x4 acc[4][2];
  gemm128_w8(P + ((size_t)(b * 2048 + ts * 128)) * 2048,
             vT + ((size_t)(b * 1024 + td * 128)) * 2048,
             2048, 2048, (ts + 1) * 128, As, Bs, acc);

  const int lane = threadIdx.x & 63, wave = threadIdx.x >> 6;
  const int wm = wave >> 2, wn = wave & 3, rr = lane & 15, qq = lane >> 4;
#pragma unroll
  for (int i = 0; i < 4; ++i) {
    int s0 = ts * 128 + wm * 64 + i * 16 + qq * 4;
    float4 r4 = *(const float4*)(rsum + b * 2048 + s0);
    float rv[4] = {__builtin_amdgcn_rcpf(r4.x), __builtin_amdgcn_rcpf(r4.y),
                   __builtin_amdgcn_rcpf(r4.z), __builtin_amdgcn_rcpf(r4.w)};
#pragma unroll
    for (int reg = 0; reg < 4; ++reg) {
      int srow = s0 + reg;
#pragma unroll
      for (int j = 0; j < 2; ++j) {
        int dcol = td * 128 + wn * 32 + j * 16 + rr;
        out[((size_t)(b * 2048 + srow)) * 1024 + dcol] =
            acc[i][j][reg] * rv[reg];
      }
    }
  }
}

// ---------------------------------------------------------------------------
// launch
// ---------------------------------------------------------------------------
extern "C" void kernel_launch(void* const* d_in, const int* in_sizes, int n_in,
                              void* d_out, int out_size, void* d_ws,
                              size_t ws_size, hipStream_t stream) {
  const float* x  = (const float*)d_in[0];
  const float* Wk = (const float*)d_in[1];
  const float* bk = (const float*)d_in[2];
  const float* Wq = (const float*)d_in[3];
  const float* bq = (const float*)d_in[4];
  const float* Wv = (const float*)d_in[5];
  const float* bv = (const float*)d_in[6];
  float* out = (float*)d_out;

  char* ws = (char*)d_ws;
  const size_t MB = 1ull << 20;
  // Aliased layout (86 MB + 32 KB): P overlays xh/wh (dead by scores).
  unsigned short* xh = (unsigned short*)(ws + 0);        // 16 MB  [0,16)
  unsigned short* wh = (unsigned short*)(ws + 16 * MB);  //  6 MB  [16,22)
  unsigned short* P  = (unsigned short*)(ws + 0);        // 32 MB  [0,32) alias
  unsigned short* kh = (unsigned short*)(ws + 38 * MB);  // 16 MB  [38,54)
  unsigned short* qh = (unsigned short*)(ws + 54 * MB);  // 16 MB  [54,70)
  unsigned short* vT = (unsigned short*)(ws + 70 * MB);  // 16 MB  [70,86)
  float* rsum = (float*)(ws + 86 * MB);                  // 32 KB

  // 1) converts (x + 3 W) + rsum zero-init (last 8 blocks)
  cvt_kernel<<<11272, 256, 0, stream>>>(x, Wk, Wq, Wv, xh, rsum);
  // 2) QKV projections; z=2 operand-swapped -> writes vT directly
  qkv_gemm_kernel<<<dim3(24, 64), 256, 0, stream>>>(xh, wh, bk, bq, bv,
                                                    kh, qh, vT);
  // 3) masked exp(scores) + fused row-sum atomics (512-thread blocks)
  scores_kernel<<<dim3(136, 4), 512, 0, stream>>>(kh, qh, P, rsum);
  // 4) (P @ v) * (1/rsum) -> out (512-thread blocks)
  pv_gemm_kernel<<<dim3(8, 16, 4), 512, 0, stream>>>(P, vT, rsum, out);
}

// Round 10
// 252.721 us; speedup vs baseline: 1.0002x; 1.0002x over previous
//
#include <hip/hip_runtime.h>
#include <cstdint>

// ---------------------------------------------------------------------------
// DefaultAttention: x[4,2048,1024] fp32; k=xWk^T+bk, q=xWq^T+bq, v=xWv^T+bv;
// sim = k q^T / 32 (causal tril), attn = softmax(sim), out = attn @ v (fp32).
// R10: scores/pv K-loop restructured to TRIPLE-buffered pipeline with inline
// asm "s_waitcnt vmcnt(4); s_barrier" (waits only the oldest staging set;
// __syncthreads' vmcnt(0) would drain the in-flight prefetch too). DMA
// latency budget: 2 compute phases instead of 1. qkv = R8 (control).
// ---------------------------------------------------------------------------

typedef __attribute__((ext_vector_type(8))) _Float16 f16x8;
typedef __attribute__((ext_vector_type(4))) float f32x4;

__device__ __forceinline__ unsigned short f2h(float x) {
  return __builtin_bit_cast(unsigned short, (_Float16)x);
}

// async global->LDS, 16B per lane; LDS dest = wave-uniform base + lane*16
__device__ __forceinline__ void lds_dma16(const void* g, void* l) {
  auto gp = reinterpret_cast<const __attribute__((address_space(1))) void*>(
      reinterpret_cast<uintptr_t>(g));
  auto lp = reinterpret_cast<__attribute__((address_space(3))) void*>(
      reinterpret_cast<uintptr_t>(l));
  __builtin_amdgcn_global_load_lds(gp, lp, 16, 0, 0);
}

// ---------------------------------------------------------------------------
// gemm128 (dbuf, 256 thr): C[128x128] += A[128xK] * B[128xK]^T. BK=32,
// XOR-swizzled LDS, double-buffered single-barrier pipeline (R4-verified).
// Used by qkv (multi-round launch, ~6 blocks/CU rotation hides the rest).
// ---------------------------------------------------------------------------
__device__ __forceinline__ void gemm128(const unsigned short* __restrict__ Ag,
                                        const unsigned short* __restrict__ Bg,
                                        int lda, int ldb, int nk,
                                        unsigned short* As, unsigned short* Bs,
                                        f32x4 acc[4][4]) {
  const int tid = threadIdx.x;
  const int lane = tid & 63, wave = tid >> 6;
  const int wm = wave >> 1, wn = wave & 1;
  const int sr = lane >> 2;                               // staging row in chunk
  const int scb = (((lane & 3) ^ ((lane >> 3) & 3)) * 8); // swizzled src col
  const int rr = lane & 15, qq = lane >> 4;
  const int slot = ((qq ^ ((rr >> 1) & 3)) * 8);          // swizzled read col

#pragma unroll
  for (int i = 0; i < 4; ++i)
#pragma unroll
    for (int j = 0; j < 4; ++j) {
      f32x4 z = {0.f, 0.f, 0.f, 0.f};
      acc[i][j] = z;
    }

#pragma unroll
  for (int c = 0; c < 2; ++c) {
    int chunk = wave * 2 + c;
    int row = chunk * 16 + sr;
    lds_dma16(Ag + (size_t)row * lda + scb, As + chunk * 512);
    lds_dma16(Bg + (size_t)row * ldb + scb, Bs + chunk * 512);
  }

  int buf = 0;
  for (int k0 = 0; k0 < nk; k0 += 32) {
    __syncthreads();  // drains staging issued one compute-phase ago
    const int kn = k0 + 32;
    if (kn < nk) {
      unsigned short* An = As + (buf ^ 1) * 4096;
      unsigned short* Bn = Bs + (buf ^ 1) * 4096;
#pragma unroll
      for (int c = 0; c < 2; ++c) {
        int chunk = wave * 2 + c;
        int row = chunk * 16 + sr;
        lds_dma16(Ag + (size_t)row * lda + kn + scb, An + chunk * 512);
        lds_dma16(Bg + (size_t)row * ldb + kn + scb, Bn + chunk * 512);
      }
    }

    f16x8 af[4], bf[4];
    const unsigned short* Ar = As + buf * 4096 + (wm * 64 + rr) * 32 + slot;
    const unsigned short* Br = Bs + buf * 4096 + (wn * 64 + rr) * 32 + slot;
#pragma unroll
    for (int i = 0; i < 4; ++i) af[i] = *(const f16x8*)(Ar + i * 512);
#pragma unroll
    for (int j = 0; j < 4; ++j) bf[j] = *(const f16x8*)(Br + j * 512);
#pragma unroll
    for (int i = 0; i < 4; ++i)
#pragma unroll
      for (int j = 0; j < 4; ++j)
        acc[i][j] = __builtin_amdgcn_mfma_f32_16x16x32_f16(af[i], bf[j],
                                                           acc[i][j], 0, 0, 0);
    buf ^= 1;
  }
}

// ---------------------------------------------------------------------------
// gemm128_p3 (triple-buffer, 256 thr): same tile/swizzle, 3x16KB LDS stages,
// fine-grained vmcnt barrier. Per wave per set: 4 DMAs (2 A + 2 B chunks).
// At barrier of iter i: in flight = set i (4) + set i+1 (4, issued iter i-1)
// -> "s_waitcnt vmcnt(4)" retires exactly set i (vmcnt is in-order), set i+1
// stays in flight across the barrier. Set i+2 is issued AFTER the barrier
// (its buffer was last read at iter i-1; barrier i separates).
// ---------------------------------------------------------------------------
__device__ __forceinline__ void gemm128_p3(
    const unsigned short* __restrict__ Ag, const unsigned short* __restrict__ Bg,
    int lda, int ldb, int nk, unsigned short* As, unsigned short* Bs,
    f32x4 acc[4][4]) {
  const int tid = threadIdx.x;
  const int lane = tid & 63, wave = tid >> 6;
  const int wm = wave >> 1, wn = wave & 1;
  const int sr = lane >> 2;
  const int scb = (((lane & 3) ^ ((lane >> 3) & 3)) * 8);
  const int rr = lane & 15, qq = lane >> 4;
  const int slot = ((qq ^ ((rr >> 1) & 3)) * 8);

#pragma unroll
  for (int i = 0; i < 4; ++i)
#pragma unroll
    for (int j = 0; j < 4; ++j) {
      f32x4 z = {0.f, 0.f, 0.f, 0.f};
      acc[i][j] = z;
    }

  // prologue: stage sets 0,1 into bufs 0,1
#pragma unroll
  for (int c = 0; c < 2; ++c) {
    int chunk = wave * 2 + c;
    int row = chunk * 16 + sr;
    lds_dma16(Ag + (size_t)row * lda + scb, As + chunk * 512);
    lds_dma16(Bg + (size_t)row * ldb + scb, Bs + chunk * 512);
  }
  if (nk > 32) {
#pragma unroll
    for (int c = 0; c < 2; ++c) {
      int chunk = wave * 2 + c;
      int row = chunk * 16 + sr;
      lds_dma16(Ag + (size_t)row * lda + 32 + scb, As + 4096 + chunk * 512);
      lds_dma16(Bg + (size_t)row * ldb + 32 + scb, Bs + 4096 + chunk * 512);
    }
  }

  int buf = 0;
  for (int k0 = 0; k0 < nk; k0 += 32) {
    if (k0 + 32 < nk)
      asm volatile("s_waitcnt vmcnt(4)\n\ts_barrier" ::: "memory");
    else
      asm volatile("s_waitcnt vmcnt(0)\n\ts_barrier" ::: "memory");

    const int kn = k0 + 64;
    if (kn < nk) {
      int nb = buf + 2; if (nb >= 3) nb -= 3;
      unsigned short* An = As + nb * 4096;
      unsigned short* Bn = Bs + nb * 4096;
#pragma unroll
      for (int c = 0; c < 2; ++c) {
        int chunk = wave * 2 + c;
        int row = chunk * 16 + sr;
        lds_dma16(Ag + (size_t)row * lda + kn + scb, An + chunk * 512);
        lds_dma16(Bg + (size_t)row * ldb + kn + scb, Bn + chunk * 512);
      }
    }

    f16x8 af[4], bf[4];
    const unsigned short* Ar = As + buf * 4096 + (wm * 64 + rr) * 32 + slot;
    const unsigned short* Br = Bs + buf * 4096 + (wn * 64 + rr) * 32 + slot;
#pragma unroll
    for (int i = 0; i < 4; ++i) af[i] = *(const f16x8*)(Ar + i * 512);
#pragma unroll
    for (int j = 0; j < 4; ++j) bf[j] = *(const f16x8*)(Br + j * 512);
#pragma unroll
    for (int i = 0; i < 4; ++i)
#pragma unroll
      for (int j = 0; j < 4; ++j)
        acc[i][j] = __builtin_amdgcn_mfma_f32_16x16x32_f16(af[i], bf[j],
                                                           acc[i][j], 0, 0, 0);
    buf += 1; if (buf == 3) buf = 0;
  }
}

// ---------------------------------------------------------------------------
// fp32 -> f16 convert: x then Wk,Wq,Wv into contiguous [xh | wh];
// last 8 blocks zero rsum (8192 floats).
// ---------------------------------------------------------------------------
__global__ void cvt_kernel(const float* __restrict__ x,
                           const float* __restrict__ w0,
                           const float* __restrict__ w1,
                           const float* __restrict__ w2,
                           unsigned short* __restrict__ dst,
                           float* __restrict__ rsum) {
  int i = blockIdx.x * 256 + threadIdx.x;
  if (i >= 2883584) {
    int z2 = i - 2883584;
    float4 z = {0.f, 0.f, 0.f, 0.f};
    ((float4*)rsum)[z2] = z;
    return;
  }
  const float* s;
  size_t si;
  if (i < 2097152) {
    s = x; si = i;
  } else {
    int j = i - 2097152;
    int z = j >> 18;
    s = (z == 0) ? w0 : ((z == 1) ? w1 : w2);
    si = j & 262143;
  }
  float4 f = ((const float4*)s)[si];
  ushort4 u;
  u.x = f2h(f.x); u.y = f2h(f.y); u.z = f2h(f.z); u.w = f2h(f.w);
  ((ushort4*)dst)[i] = u;
}

// ---------------------------------------------------------------------------
// QKV projection, grid (24, 64): x = z*8 + tn (z fast -> xh slab shared by
// all 24 blocks of a tm), y = tm.
//   z=0/1: C[t, f] = xh[t-slab] . W[f-tile]^T  -> kh/qh[t*1024 + f]
//   z=2  : C[d, t] = Wv[d-tile] . xh[t-slab]^T -> vT[b][d][t]  (direct)
// ---------------------------------------------------------------------------
__global__ __launch_bounds__(256) void qkv_gemm_kernel(
    const unsigned short* __restrict__ xh, const unsigned short* __restrict__ wh,
    const float* __restrict__ bk, const float* __restrict__ bq,
    const float* __restrict__ bv, unsigned short* __restrict__ kh,
    unsigned short* __restrict__ qh, unsigned short* __restrict__ vT) {
  __shared__ unsigned short As[2 * 128 * 32], Bs[2 * 128 * 32];
  const int tn = blockIdx.x & 7, z = blockIdx.x >> 3;
  const unsigned short* W = wh + (size_t)z * 1048576;
  const int tm = blockIdx.y;

  const unsigned short* Ag = (z == 2) ? (W + (size_t)tn * 128 * 1024)
                                      : (xh + (size_t)tm * 128 * 1024);
  const unsigned short* Bg = (z == 2) ? (xh + (size_t)tm * 128 * 1024)
                                      : (W + (size_t)tn * 128 * 1024);

  f32x4 acc[4][4];
  gemm128(Ag, Bg, 1024, 1024, 1024, As, Bs, acc);

  const int lane = threadIdx.x & 63, wave = threadIdx.x >> 6;
  const int wm = wave >> 1, wn = wave & 1, rr = lane & 15, qq = lane >> 4;

  if (z == 2) {
    // rows = d, cols = t; bias is per-row (float4 over reg)
#pragma unroll
    for (int i = 0; i < 4; ++i) {
      int d0 = tn * 128 + wm * 64 + i * 16 + qq * 4;
      float4 bi = *(const float4*)(bv + d0);
      float bir[4] = {bi.x, bi.y, bi.z, bi.w};
#pragma unroll
      for (int reg = 0; reg < 4; ++reg) {
        int d = d0 + reg;
#pragma unroll
        for (int j = 0; j < 4; ++j) {
          int tg = tm * 128 + wn * 64 + j * 16 + rr;  // global token
          int bb = tg >> 11, tt = tg & 2047;
          vT[((size_t)(bb * 1024 + d)) * 2048 + tt] =
              f2h(acc[i][j][reg] + bir[reg]);
        }
      }
    }
  } else {
    const float* bias = (z == 0) ? bk : bq;
    unsigned short* dst = (z == 0) ? kh : qh;
    float bj[4];
#pragma unroll
    for (int j = 0; j < 4; ++j)
      bj[j] = bias[tn * 128 + wn * 64 + j * 16 + rr];
#pragma unroll
    for (int i = 0; i < 4; ++i)
#pragma unroll
      for (int reg = 0; reg < 4; ++reg) {
        int gm = tm * 128 + wm * 64 + i * 16 + qq * 4 + reg;
#pragma unroll
        for (int j = 0; j < 4; ++j) {
          int gc = tn * 128 + wn * 64 + j * 16 + rr;
          dst[(size_t)gm * 1024 + gc] = f2h(acc[i][j][reg] + bj[j]);
        }
      }
  }
}

// ---------------------------------------------------------------------------
// scores: P[b,s,t] = exp(k[s].q[t]/32 - 4) for t<=s else 0  (f16), plus
// fused row-sum atomics. Triangular grid (136,4). Triple-buffer pipeline.
// ---------------------------------------------------------------------------
__global__ __launch_bounds__(256) void scores_kernel(
    const unsigned short* __restrict__ kh, const unsigned short* __restrict__ qh,
    unsigned short* __restrict__ P, float* __restrict__ rsum) {
  const int b = blockIdx.y;
  int idx = blockIdx.x;
  int ts = (int)((sqrtf(8.0f * idx + 1.0f) - 1.0f) * 0.5f);
  while ((ts + 1) * (ts + 2) / 2 <= idx) ++ts;
  while (ts * (ts + 1) / 2 > idx) --ts;
  const int tt = idx - ts * (ts + 1) / 2;
  __shared__ unsigned short As[3 * 128 * 32], Bs[3 * 128 * 32];

  f32x4 acc[4][4];
  gemm128_p3(kh + ((size_t)(b * 2048 + ts * 128)) * 1024,
             qh + ((size_t)(b * 2048 + tt * 128)) * 1024,
             1024, 1024, 1024, As, Bs, acc);

  const int lane = threadIdx.x & 63, wave = threadIdx.x >> 6;
  const int wm = wave >> 1, wn = wave & 1, rr = lane & 15, qq = lane >> 4;
  unsigned short* Pb = P + (size_t)b * 2048 * 2048;
  float* rs = rsum + b * 2048;
#pragma unroll
  for (int i = 0; i < 4; ++i)
#pragma unroll
    for (int reg = 0; reg < 4; ++reg) {
      int srow = ts * 128 + wm * 64 + i * 16 + qq * 4 + reg;
      float p = 0.f;
#pragma unroll
      for (int j = 0; j < 4; ++j) {
        int tcol = tt * 128 + wn * 64 + j * 16 + rr;
        float e = (tcol <= srow) ? __expf(acc[i][j][reg] * 0.03125f - 4.0f)
                                 : 0.0f;
        Pb[(size_t)srow * 2048 + tcol] = f2h(e);
        p += e;
      }
#pragma unroll
      for (int off = 1; off < 16; off <<= 1) p += __shfl_xor(p, off);
      if (rr == 0) atomicAdd(rs + srow, p);
    }
}

// ---------------------------------------------------------------------------
// pv: out[b,s,d] = (1/rsum[b,s]) * sum_t P[b,s,t] * vT[b,d,t]   (fp32 out)
// grid (8,16,4); K truncated to (ts+1)*128; y reversed (big-K first).
// Triple-buffer pipeline.
// ---------------------------------------------------------------------------
__global__ __launch_bounds__(256) void pv_gemm_kernel(
    const unsigned short* __restrict__ P, const unsigned short* __restrict__ vT,
    const float* __restrict__ rsum, float* __restrict__ out) {
  const int td = blockIdx.x, ts = 15 - blockIdx.y, b = blockIdx.z;
  __shared__ unsigned short As[3 * 128 * 32], Bs[3 * 128 * 32];

  f32x4 acc[4][4];
  gemm128_p3(P + ((size_t)(b * 2048 + ts * 128)) * 2048,
             vT + ((size_t)(b * 1024 + td * 128)) * 2048,
             2048, 2048, (ts + 1) * 128, As, Bs, acc);

  const int lane = threadIdx.x & 63, wave = threadIdx.x >> 6;
  const int wm = wave >> 1, wn = wave & 1, rr = lane & 15, qq = lane >> 4;
#pragma unroll
  for (int i = 0; i < 4; ++i) {
    int s0 = ts * 128 + wm * 64 + i * 16 + qq * 4;
    float4 r4 = *(const float4*)(rsum + b * 2048 + s0);
    float rv[4] = {__builtin_amdgcn_rcpf(r4.x), __builtin_amdgcn_rcpf(r4.y),
                   __builtin_amdgcn_rcpf(r4.z), __builtin_amdgcn_rcpf(r4.w)};
#pragma unroll
    for (int reg = 0; reg < 4; ++reg) {
      int srow = s0 + reg;
#pragma unroll
      for (int j = 0; j < 4; ++j) {
        int dcol = td * 128 + wn * 64 + j * 16 + rr;
        out[((size_t)(b * 2048 + srow)) * 1024 + dcol] =
            acc[i][j][reg] * rv[reg];
      }
    }
  }
}

// ---------------------------------------------------------------------------
// launch
// ---------------------------------------------------------------------------
extern "C" void kernel_launch(void* const* d_in, const int* in_sizes, int n_in,
                              void* d_out, int out_size, void* d_ws,
                              size_t ws_size, hipStream_t stream) {
  const float* x  = (const float*)d_in[0];
  const float* Wk = (const float*)d_in[1];
  const float* bk = (const float*)d_in[2];
  const float* Wq = (const float*)d_in[3];
  const float* bq = (const float*)d_in[4];
  const float* Wv = (const float*)d_in[5];
  const float* bv = (const float*)d_in[6];
  float* out = (float*)d_out;

  char* ws = (char*)d_ws;
  const size_t MB = 1ull << 20;
  // Aliased layout (86 MB + 32 KB): P overlays xh/wh (dead by scores).
  unsigned short* xh = (unsigned short*)(ws + 0);        // 16 MB  [0,16)
  unsigned short* wh = (unsigned short*)(ws + 16 * MB);  //  6 MB  [16,22)
  unsigned short* P  = (unsigned short*)(ws + 0);        // 32 MB  [0,32) alias
  unsigned short* kh = (unsigned short*)(ws + 38 * MB);  // 16 MB  [38,54)
  unsigned short* qh = (unsigned short*)(ws + 54 * MB);  // 16 MB  [54,70)
  unsigned short* vT = (unsigned short*)(ws + 70 * MB);  // 16 MB  [70,86)
  float* rsum = (float*)(ws + 86 * MB);                  // 32 KB

  // 1) converts (x + 3 W) + rsum zero-init (last 8 blocks)
  cvt_kernel<<<11272, 256, 0, stream>>>(x, Wk, Wq, Wv, xh, rsum);
  // 2) QKV projections; z=2 operand-swapped -> writes vT directly
  qkv_gemm_kernel<<<dim3(24, 64), 256, 0, stream>>>(xh, wh, bk, bq, bv,
                                                    kh, qh, vT);
  // 3) masked exp(scores) + fused row-sum atomics (triple-buffer pipeline)
  scores_kernel<<<dim3(136, 4), 256, 0, stream>>>(kh, qh, P, rsum);
  // 4) (P @ v) * (1/rsum) -> out (triple-buffer pipeline)
  pv_gemm_kernel<<<dim3(8, 16, 4), 256, 0, stream>>>(P, vT, rsum, out);
}

// Round 11
// 239.909 us; speedup vs baseline: 1.0536x; 1.0534x over previous
//
#include <hip/hip_runtime.h>
#include <cstdint>

// ---------------------------------------------------------------------------
// DefaultAttention: x[4,2048,1024] fp32; k=xWk^T+bk, q=xWq^T+bq, v=xWv^T+bv;
// sim = k q^T / 32 (causal tril), attn = softmax(sim), out = attn @ v (fp32).
// R11: scores/pv use BK=64 double-buffered K-loop (64 KB LDS) -- their grid
// (2.1 blocks/CU) bounds occupancy, so big LDS is free for them (unlike qkv,
// R3), and halving the barrier count halves the dominant DMA-latency stalls.
// qkv keeps the R4/R8 BK=32 dbuf (multi-round launch, occupancy-sensitive).
// ---------------------------------------------------------------------------

typedef __attribute__((ext_vector_type(8))) _Float16 f16x8;
typedef __attribute__((ext_vector_type(4))) float f32x4;

__device__ __forceinline__ unsigned short f2h(float x) {
  return __builtin_bit_cast(unsigned short, (_Float16)x);
}

// async global->LDS, 16B per lane; LDS dest = wave-uniform base + lane*16
__device__ __forceinline__ void lds_dma16(const void* g, void* l) {
  auto gp = reinterpret_cast<const __attribute__((address_space(1))) void*>(
      reinterpret_cast<uintptr_t>(g));
  auto lp = reinterpret_cast<__attribute__((address_space(3))) void*>(
      reinterpret_cast<uintptr_t>(l));
  __builtin_amdgcn_global_load_lds(gp, lp, 16, 0, 0);
}

// ---------------------------------------------------------------------------
// gemm128 (BK=32 dbuf, 256 thr): C[128x128] += A[128xK] * B[128xK]^T.
// XOR-swizzled LDS, double-buffered single-barrier pipeline (R4-verified).
// ---------------------------------------------------------------------------
__device__ __forceinline__ void gemm128(const unsigned short* __restrict__ Ag,
                                        const unsigned short* __restrict__ Bg,
                                        int lda, int ldb, int nk,
                                        unsigned short* As, unsigned short* Bs,
                                        f32x4 acc[4][4]) {
  const int tid = threadIdx.x;
  const int lane = tid & 63, wave = tid >> 6;
  const int wm = wave >> 1, wn = wave & 1;
  const int sr = lane >> 2;                               // staging row in chunk
  const int scb = (((lane & 3) ^ ((lane >> 3) & 3)) * 8); // swizzled src col
  const int rr = lane & 15, qq = lane >> 4;
  const int slot = ((qq ^ ((rr >> 1) & 3)) * 8);          // swizzled read col

#pragma unroll
  for (int i = 0; i < 4; ++i)
#pragma unroll
    for (int j = 0; j < 4; ++j) {
      f32x4 z = {0.f, 0.f, 0.f, 0.f};
      acc[i][j] = z;
    }

#pragma unroll
  for (int c = 0; c < 2; ++c) {
    int chunk = wave * 2 + c;
    int row = chunk * 16 + sr;
    lds_dma16(Ag + (size_t)row * lda + scb, As + chunk * 512);
    lds_dma16(Bg + (size_t)row * ldb + scb, Bs + chunk * 512);
  }

  int buf = 0;
  for (int k0 = 0; k0 < nk; k0 += 32) {
    __syncthreads();  // drains staging issued one compute-phase ago
    const int kn = k0 + 32;
    if (kn < nk) {
      unsigned short* An = As + (buf ^ 1) * 4096;
      unsigned short* Bn = Bs + (buf ^ 1) * 4096;
#pragma unroll
      for (int c = 0; c < 2; ++c) {
        int chunk = wave * 2 + c;
        int row = chunk * 16 + sr;
        lds_dma16(Ag + (size_t)row * lda + kn + scb, An + chunk * 512);
        lds_dma16(Bg + (size_t)row * ldb + kn + scb, Bn + chunk * 512);
      }
    }

    f16x8 af[4], bf[4];
    const unsigned short* Ar = As + buf * 4096 + (wm * 64 + rr) * 32 + slot;
    const unsigned short* Br = Bs + buf * 4096 + (wn * 64 + rr) * 32 + slot;
#pragma unroll
    for (int i = 0; i < 4; ++i) af[i] = *(const f16x8*)(Ar + i * 512);
#pragma unroll
    for (int j = 0; j < 4; ++j) bf[j] = *(const f16x8*)(Br + j * 512);
#pragma unroll
    for (int i = 0; i < 4; ++i)
#pragma unroll
      for (int j = 0; j < 4; ++j)
        acc[i][j] = __builtin_amdgcn_mfma_f32_16x16x32_f16(af[i], bf[j],
                                                           acc[i][j], 0, 0, 0);
    buf ^= 1;
  }
}

// ---------------------------------------------------------------------------
// gemm128_k64 (BK=64 dbuf, 256 thr): 2x16KB stages per matrix (64 KB LDS).
// R3-verified swizzle: LDS slot s of row r holds src col-block s^(r&7);
// readers use slot (cb ^ (rr&7)). 16 iters for nk=1024 -> half the barrier
// stalls; 32 MFMA/wave between barriers.
// ---------------------------------------------------------------------------
__device__ __forceinline__ void gemm128_k64(
    const unsigned short* __restrict__ Ag, const unsigned short* __restrict__ Bg,
    int lda, int ldb, int nk, unsigned short* As, unsigned short* Bs,
    f32x4 acc[4][4]) {
  const int tid = threadIdx.x;
  const int lane = tid & 63, wave = tid >> 6;
  const int wm = wave >> 1, wn = wave & 1;
  const int sr = lane >> 3;                     // staging row within 8-row chunk
  const int scb = ((lane & 7) ^ sr) * 8;        // swizzled source col (ush)
  const int rr = lane & 15, qq = lane >> 4;
  const int slot0 = ((qq) ^ (rr & 7)) * 8;      // k-half 0 read col
  const int slot1 = ((4 + qq) ^ (rr & 7)) * 8;  // k-half 1 read col

#pragma unroll
  for (int i = 0; i < 4; ++i)
#pragma unroll
    for (int j = 0; j < 4; ++j) {
      f32x4 z = {0.f, 0.f, 0.f, 0.f};
      acc[i][j] = z;
    }

  // prologue: stage k=0 into buf 0 (16 chunks of 8 rows; wave w: 4w..4w+3)
#pragma unroll
  for (int c = 0; c < 4; ++c) {
    int chunk = wave * 4 + c;
    int row = chunk * 8 + sr;
    lds_dma16(Ag + (size_t)row * lda + scb, As + chunk * 512);
    lds_dma16(Bg + (size_t)row * ldb + scb, Bs + chunk * 512);
  }

  int buf = 0;
  for (int k0 = 0; k0 < nk; k0 += 64) {
    __syncthreads();  // drains staging issued one compute-phase ago
    const int kn = k0 + 64;
    if (kn < nk) {
      unsigned short* An = As + (buf ^ 1) * 8192;
      unsigned short* Bn = Bs + (buf ^ 1) * 8192;
#pragma unroll
      for (int c = 0; c < 4; ++c) {
        int chunk = wave * 4 + c;
        int row = chunk * 8 + sr;
        lds_dma16(Ag + (size_t)row * lda + kn + scb, An + chunk * 512);
        lds_dma16(Bg + (size_t)row * ldb + kn + scb, Bn + chunk * 512);
      }
    }

    const unsigned short* Ar = As + buf * 8192 + (wm * 64 + rr) * 64;
    const unsigned short* Br = Bs + buf * 8192 + (wn * 64 + rr) * 64;
    {
      f16x8 af[4], bf[4];
#pragma unroll
      for (int i = 0; i < 4; ++i) af[i] = *(const f16x8*)(Ar + i * 1024 + slot0);
#pragma unroll
      for (int j = 0; j < 4; ++j) bf[j] = *(const f16x8*)(Br + j * 1024 + slot0);
#pragma unroll
      for (int i = 0; i < 4; ++i)
#pragma unroll
        for (int j = 0; j < 4; ++j)
          acc[i][j] = __builtin_amdgcn_mfma_f32_16x16x32_f16(af[i], bf[j],
                                                             acc[i][j], 0, 0, 0);
    }
    {
      f16x8 af[4], bf[4];
#pragma unroll
      for (int i = 0; i < 4; ++i) af[i] = *(const f16x8*)(Ar + i * 1024 + slot1);
#pragma unroll
      for (int j = 0; j < 4; ++j) bf[j] = *(const f16x8*)(Br + j * 1024 + slot1);
#pragma unroll
      for (int i = 0; i < 4; ++i)
#pragma unroll
        for (int j = 0; j < 4; ++j)
          acc[i][j] = __builtin_amdgcn_mfma_f32_16x16x32_f16(af[i], bf[j],
                                                             acc[i][j], 0, 0, 0);
    }
    buf ^= 1;
  }
}

// ---------------------------------------------------------------------------
// fp32 -> f16 convert: x then Wk,Wq,Wv into contiguous [xh | wh];
// last 8 blocks zero rsum (8192 floats).
// ---------------------------------------------------------------------------
__global__ void cvt_kernel(const float* __restrict__ x,
                           const float* __restrict__ w0,
                           const float* __restrict__ w1,
                           const float* __restrict__ w2,
                           unsigned short* __restrict__ dst,
                           float* __restrict__ rsum) {
  int i = blockIdx.x * 256 + threadIdx.x;
  if (i >= 2883584) {
    int z2 = i - 2883584;
    float4 z = {0.f, 0.f, 0.f, 0.f};
    ((float4*)rsum)[z2] = z;
    return;
  }
  const float* s;
  size_t si;
  if (i < 2097152) {
    s = x; si = i;
  } else {
    int j = i - 2097152;
    int z = j >> 18;
    s = (z == 0) ? w0 : ((z == 1) ? w1 : w2);
    si = j & 262143;
  }
  float4 f = ((const float4*)s)[si];
  ushort4 u;
  u.x = f2h(f.x); u.y = f2h(f.y); u.z = f2h(f.z); u.w = f2h(f.w);
  ((ushort4*)dst)[i] = u;
}

// ---------------------------------------------------------------------------
// QKV projection, grid (24, 64): x = z*8 + tn (z fast -> xh slab shared by
// all 24 blocks of a tm), y = tm.
//   z=0/1: C[t, f] = xh[t-slab] . W[f-tile]^T  -> kh/qh[t*1024 + f]
//   z=2  : C[d, t] = Wv[d-tile] . xh[t-slab]^T -> vT[b][d][t]  (direct)
// ---------------------------------------------------------------------------
__global__ __launch_bounds__(256) void qkv_gemm_kernel(
    const unsigned short* __restrict__ xh, const unsigned short* __restrict__ wh,
    const float* __restrict__ bk, const float* __restrict__ bq,
    const float* __restrict__ bv, unsigned short* __restrict__ kh,
    unsigned short* __restrict__ qh, unsigned short* __restrict__ vT) {
  __shared__ unsigned short As[2 * 128 * 32], Bs[2 * 128 * 32];
  const int tn = blockIdx.x & 7, z = blockIdx.x >> 3;
  const unsigned short* W = wh + (size_t)z * 1048576;
  const int tm = blockIdx.y;

  const unsigned short* Ag = (z == 2) ? (W + (size_t)tn * 128 * 1024)
                                      : (xh + (size_t)tm * 128 * 1024);
  const unsigned short* Bg = (z == 2) ? (xh + (size_t)tm * 128 * 1024)
                                      : (W + (size_t)tn * 128 * 1024);

  f32x4 acc[4][4];
  gemm128(Ag, Bg, 1024, 1024, 1024, As, Bs, acc);

  const int lane = threadIdx.x & 63, wave = threadIdx.x >> 6;
  const int wm = wave >> 1, wn = wave & 1, rr = lane & 15, qq = lane >> 4;

  if (z == 2) {
    // rows = d, cols = t; bias is per-row (float4 over reg)
#pragma unroll
    for (int i = 0; i < 4; ++i) {
      int d0 = tn * 128 + wm * 64 + i * 16 + qq * 4;
      float4 bi = *(const float4*)(bv + d0);
      float bir[4] = {bi.x, bi.y, bi.z, bi.w};
#pragma unroll
      for (int reg = 0; reg < 4; ++reg) {
        int d = d0 + reg;
#pragma unroll
        for (int j = 0; j < 4; ++j) {
          int tg = tm * 128 + wn * 64 + j * 16 + rr;  // global token
          int bb = tg >> 11, tt = tg & 2047;
          vT[((size_t)(bb * 1024 + d)) * 2048 + tt] =
              f2h(acc[i][j][reg] + bir[reg]);
        }
      }
    }
  } else {
    const float* bias = (z == 0) ? bk : bq;
    unsigned short* dst = (z == 0) ? kh : qh;
    float bj[4];
#pragma unroll
    for (int j = 0; j < 4; ++j)
      bj[j] = bias[tn * 128 + wn * 64 + j * 16 + rr];
#pragma unroll
    for (int i = 0; i < 4; ++i)
#pragma unroll
      for (int reg = 0; reg < 4; ++reg) {
        int gm = tm * 128 + wm * 64 + i * 16 + qq * 4 + reg;
#pragma unroll
        for (int j = 0; j < 4; ++j) {
          int gc = tn * 128 + wn * 64 + j * 16 + rr;
          dst[(size_t)gm * 1024 + gc] = f2h(acc[i][j][reg] + bj[j]);
        }
      }
  }
}

// ---------------------------------------------------------------------------
// scores: P[b,s,t] = exp(k[s].q[t]/32 - 4) for t<=s else 0  (f16), plus
// fused row-sum atomics. Triangular grid (136,4). BK=64 dbuf pipeline.
// ---------------------------------------------------------------------------
__global__ __launch_bounds__(256) void scores_kernel(
    const unsigned short* __restrict__ kh, const unsigned short* __restrict__ qh,
    unsigned short* __restrict__ P, float* __restrict__ rsum) {
  const int b = blockIdx.y;
  int idx = blockIdx.x;
  int ts = (int)((sqrtf(8.0f * idx + 1.0f) - 1.0f) * 0.5f);
  while ((ts + 1) * (ts + 2) / 2 <= idx) ++ts;
  while (ts * (ts + 1) / 2 > idx) --ts;
  const int tt = idx - ts * (ts + 1) / 2;
  __shared__ unsigned short As[2 * 128 * 64], Bs[2 * 128 * 64];

  f32x4 acc[4][4];
  gemm128_k64(kh + ((size_t)(b * 2048 + ts * 128)) * 1024,
              qh + ((size_t)(b * 2048 + tt * 128)) * 1024,
              1024, 1024, 1024, As, Bs, acc);

  const int lane = threadIdx.x & 63, wave = threadIdx.x >> 6;
  const int wm = wave >> 1, wn = wave & 1, rr = lane & 15, qq = lane >> 4;
  unsigned short* Pb = P + (size_t)b * 2048 * 2048;
  float* rs = rsum + b * 2048;
#pragma unroll
  for (int i = 0; i < 4; ++i)
#pragma unroll
    for (int reg = 0; reg < 4; ++reg) {
      int srow = ts * 128 + wm * 64 + i * 16 + qq * 4 + reg;
      float p = 0.f;
#pragma unroll
      for (int j = 0; j < 4; ++j) {
        int tcol = tt * 128 + wn * 64 + j * 16 + rr;
        float e = (tcol <= srow) ? __expf(acc[i][j][reg] * 0.03125f - 4.0f)
                                 : 0.0f;
        Pb[(size_t)srow * 2048 + tcol] = f2h(e);
        p += e;
      }
#pragma unroll
      for (int off = 1; off < 16; off <<= 1) p += __shfl_xor(p, off);
      if (rr == 0) atomicAdd(rs + srow, p);
    }
}

// ---------------------------------------------------------------------------
// pv: out[b,s,d] = (1/rsum[b,s]) * sum_t P[b,s,t] * vT[b,d,t]   (fp32 out)
// grid (8,16,4); K truncated to (ts+1)*128; y reversed (big-K first).
// BK=64 dbuf pipeline.
// ---------------------------------------------------------------------------
__global__ __launch_bounds__(256) void pv_gemm_kernel(
    const unsigned short* __restrict__ P, const unsigned short* __restrict__ vT,
    const float* __restrict__ rsum, float* __restrict__ out) {
  const int td = blockIdx.x, ts = 15 - blockIdx.y, b = blockIdx.z;
  __shared__ unsigned short As[2 * 128 * 64], Bs[2 * 128 * 64];

  f32x4 acc[4][4];
  gemm128_k64(P + ((size_t)(b * 2048 + ts * 128)) * 2048,
              vT + ((size_t)(b * 1024 + td * 128)) * 2048,
              2048, 2048, (ts + 1) * 128, As, Bs, acc);

  const int lane = threadIdx.x & 63, wave = threadIdx.x >> 6;
  const int wm = wave >> 1, wn = wave & 1, rr = lane & 15, qq = lane >> 4;
#pragma unroll
  for (int i = 0; i < 4; ++i) {
    int s0 = ts * 128 + wm * 64 + i * 16 + qq * 4;
    float4 r4 = *(const float4*)(rsum + b * 2048 + s0);
    float rv[4] = {__builtin_amdgcn_rcpf(r4.x), __builtin_amdgcn_rcpf(r4.y),
                   __builtin_amdgcn_rcpf(r4.z), __builtin_amdgcn_rcpf(r4.w)};
#pragma unroll
    for (int reg = 0; reg < 4; ++reg) {
      int srow = s0 + reg;
#pragma unroll
      for (int j = 0; j < 4; ++j) {
        int dcol = td * 128 + wn * 64 + j * 16 + rr;
        out[((size_t)(b * 2048 + srow)) * 1024 + dcol] =
            acc[i][j][reg] * rv[reg];
      }
    }
  }
}

// ---------------------------------------------------------------------------
// launch
// ---------------------------------------------------------------------------
extern "C" void kernel_launch(void* const* d_in, const int* in_sizes, int n_in,
                              void* d_out, int out_size, void* d_ws,
                              size_t ws_size, hipStream_t stream) {
  const float* x  = (const float*)d_in[0];
  const float* Wk = (const float*)d_in[1];
  const float* bk = (const float*)d_in[2];
  const float* Wq = (const float*)d_in[3];
  const float* bq = (const float*)d_in[4];
  const float* Wv = (const float*)d_in[5];
  const float* bv = (const float*)d_in[6];
  float* out = (float*)d_out;

  char* ws = (char*)d_ws;
  const size_t MB = 1ull << 20;
  // Aliased layout (86 MB + 32 KB): P overlays xh/wh (dead by scores).
  unsigned short* xh = (unsigned short*)(ws + 0);        // 16 MB  [0,16)
  unsigned short* wh = (unsigned short*)(ws + 16 * MB);  //  6 MB  [16,22)
  unsigned short* P  = (unsigned short*)(ws + 0);        // 32 MB  [0,32) alias
  unsigned short* kh = (unsigned short*)(ws + 38 * MB);  // 16 MB  [38,54)
  unsigned short* qh = (unsigned short*)(ws + 54 * MB);  // 16 MB  [54,70)
  unsigned short* vT = (unsigned short*)(ws + 70 * MB);  // 16 MB  [70,86)
  float* rsum = (float*)(ws + 86 * MB);                  // 32 KB

  // 1) converts (x + 3 W) + rsum zero-init (last 8 blocks)
  cvt_kernel<<<11272, 256, 0, stream>>>(x, Wk, Wq, Wv, xh, rsum);
  // 2) QKV projections; z=2 operand-swapped -> writes vT directly
  qkv_gemm_kernel<<<dim3(24, 64), 256, 0, stream>>>(xh, wh, bk, bq, bv,
                                                    kh, qh, vT);
  // 3) masked exp(scores) + fused row-sum atomics (BK=64 dbuf)
  scores_kernel<<<dim3(136, 4), 256, 0, stream>>>(kh, qh, P, rsum);
  // 4) (P @ v) * (1/rsum) -> out (BK=64 dbuf)
  pv_gemm_kernel<<<dim3(8, 16, 4), 256, 0, stream>>>(P, vT, rsum, out);
}